// Round 7
// baseline (548.403 us; speedup 1.0000x reference)
//
#include <hip/hip_runtime.h>

#define NNODES 50000
#define HID 128
#define NREL 9
#define NLAYERS 3
#define NEDGES 600000

#define NBINS (NREL * NNODES)          // 450000, bin = d*9+r  (d-major: row's rels contiguous)
#define SCAN_CHUNK 1024
#define NBLK ((NBINS + SCAN_CHUNK - 1) / SCAN_CHUNK)   // 440

#define KTOT (NREL * HID)               // 1152
#define GM 16                           // rows per fused block -> 3125 blocks (50000/16 exact)
#define KPITCH 1160                     // panel pitch in shorts
#define FPITCH 136                      // epilogue bf16 Et pitch (reuses As)

// prep_kernel block ranges
#define HIST_BLKS ((NEDGES + 255) / 256)            // 2344
#define EMB_BLKS  ((NNODES * HID / 8) / 256)        // 3125
#define W_BLKS    (NLAYERS * NREL)                  // 27

typedef __attribute__((ext_vector_type(8))) short short8;
typedef __attribute__((ext_vector_type(4))) float f32x4;

__device__ __forceinline__ short f2bf(float f) {
    union { float f; unsigned u; } c; c.f = f;
    unsigned r = c.u + 0x7fff + ((c.u >> 16) & 1);   // RNE
    return (short)(r >> 16);
}
__device__ __forceinline__ float bf2f(short v) {
    return __uint_as_float(((unsigned)(unsigned short)v) << 16);
}

// ---------------- prep: histogram + emb convert + W convert (one dispatch) ----------------
// Wt2[l][n][r*128+kk] = bf16(W[l][r][kk][n])   (r-major K)

__global__ __launch_bounds__(256) void prep_kernel(const int* __restrict__ dst,
                                                   const int* __restrict__ etype,
                                                   int* __restrict__ bins,
                                                   const float* __restrict__ E,
                                                   short* __restrict__ Ebf,
                                                   const float* __restrict__ W,
                                                   short* __restrict__ Wt2) {
    int b = blockIdx.x, tid = threadIdx.x;
    if (b < HIST_BLKS) {
        int e = b * 256 + tid;
        if (e < NEDGES) {
            int bin = dst[e] * NREL + etype[e];
            atomicAdd(&bins[bin], 1);
        }
    } else if (b < HIST_BLKS + EMB_BLKS) {
        int gid = (b - HIST_BLKS) * 256 + tid;
        const float* p = E + (size_t)gid * 8;
        float4 v0 = *(const float4*)p;
        float4 v1 = *(const float4*)(p + 4);
        short8 o = {f2bf(v0.x), f2bf(v0.y), f2bf(v0.z), f2bf(v0.w),
                    f2bf(v1.x), f2bf(v1.y), f2bf(v1.z), f2bf(v1.w)};
        *(short8*)(Ebf + (size_t)gid * 8) = o;
    } else {
        int lr = b - HIST_BLKS - EMB_BLKS;
        int l = lr / NREL, r = lr - l * NREL;
        const float* w = W + (size_t)lr * HID * HID;
        short* o = Wt2 + (size_t)l * HID * KTOT;
#pragma unroll 4
        for (int i = 0; i < 64; i++) {
            int elem = i * 256 + tid;
            int kk = elem >> 7, n = elem & 127;
            o[(size_t)n * KTOT + r * HID + kk] = f2bf(w[elem]);
        }
    }
}

// ---------------- scans ----------------

__global__ __launch_bounds__(256) void scan_pass1(const int* __restrict__ bins,
                                                  int* __restrict__ blocksum) {
    __shared__ int red[256];
    int b = blockIdx.x, t = threadIdx.x;
    int i0 = b * SCAN_CHUNK + t * 4;
    int s = 0;
#pragma unroll
    for (int k = 0; k < 4; k++)
        if (i0 + k < NBINS) s += bins[i0 + k];
    red[t] = s;
    __syncthreads();
    for (int off = 128; off > 0; off >>= 1) {
        if (t < off) red[t] += red[t + off];
        __syncthreads();
    }
    if (t == 0) blocksum[b] = red[0];
}

__global__ __launch_bounds__(512) void scan_pass2(const int* __restrict__ blocksum,
                                                  int* __restrict__ blockoff,
                                                  int* __restrict__ rowptr) {
    __shared__ int s[512];
    int t = threadIdx.x;
    int v = (t < NBLK) ? blocksum[t] : 0;
    s[t] = v;
    __syncthreads();
    for (int off = 1; off < 512; off <<= 1) {
        int x = (t >= off) ? s[t - off] : 0;
        __syncthreads();
        s[t] += x;
        __syncthreads();
    }
    if (t < NBLK) blockoff[t] = s[t] - v;
    if (t == 0) rowptr[NBINS] = NEDGES;
}

__global__ __launch_bounds__(256) void scan_pass3(const int* __restrict__ bins,
                                                  const int* __restrict__ blockoff,
                                                  int* __restrict__ rowptr,
                                                  int* __restrict__ cursor) {
    __shared__ int sc[256];
    int b = blockIdx.x, t = threadIdx.x;
    int i0 = b * SCAN_CHUNK + t * 4;
    int v[4], p[4];
    int s = 0;
#pragma unroll
    for (int k = 0; k < 4; k++) {
        v[k] = (i0 + k < NBINS) ? bins[i0 + k] : 0;
        p[k] = s;
        s += v[k];
    }
    sc[t] = s;
    __syncthreads();
    for (int off = 1; off < 256; off <<= 1) {
        int x = (t >= off) ? sc[t - off] : 0;
        __syncthreads();
        sc[t] += x;
        __syncthreads();
    }
    int base = blockoff[b] + (sc[t] - s);
#pragma unroll
    for (int k = 0; k < 4; k++) {
        if (i0 + k < NBINS) {
            rowptr[i0 + k] = base + p[k];
            cursor[i0 + k] = base + p[k];
        }
    }
}

__global__ void place_kernel(const int* __restrict__ dst, const int* __restrict__ src,
                             const int* __restrict__ etype,
                             int* __restrict__ cursor, int* __restrict__ bsrc) {
    int e = blockIdx.x * blockDim.x + threadIdx.x;
    if (e < 8) bsrc[NEDGES + e] = 0;     // zero the lookahead pad (never written by cursors)
    if (e < NEDGES) {
        int bin = dst[e] * NREL + etype[e];
        int pos = atomicAdd(&cursor[bin], 1);
        bsrc[pos] = src[e];
    }
}

// ---------------- fused layer: single-walk gather + full-K MFMA sweep ----------------
// Per block: 16 dest rows, 3125 blocks, 4 blocks/CU (37.7 KB LDS). d-major CSR means
// a row's 9 relations are CONTIGUOUS, r-sorted: each 16-lane row-team walks its row's
// whole edge list ONCE (8-deep groups: 8 H-slices of 16 B/lane in flight), tracking the
// current relation with a monotone boundary pointer; on each r-transition the 8-f32
// accumulator is flushed (bf16) to panel slice r and zeroed. Exactly 9 flushes/thread,
// empty slices written as zeros -> panel fully defined, no pre-zero, no atomics.
// ONE barrier, then 36-chunk MFMA (M=16, B streamed from L2), epilogue w/ cnt-bias.
// C mapping (verified): row = lq*4 + reg, col = n0 + nt*16 + lm.

__global__ __launch_bounds__(256, 4) void fused_kernel(const short* __restrict__ Hin,
                                                       const short* __restrict__ Wt2l,
                                                       const float* __restrict__ Bias, // [9][128]
                                                       const int* __restrict__ rowptr,
                                                       const int* __restrict__ bsrc,
                                                       short* __restrict__ HoutBf,     // !last
                                                       float* __restrict__ HoutF,      // last
                                                       int last) {
    __shared__ short As[GM * KPITCH];             // 37120 B; reused as Et
    __shared__ int   rp_s[GM * NREL + 2];         // 146 bin boundaries (contiguous in rowptr)

    int tid  = threadIdx.x;
    int wave = tid >> 6, lane = tid & 63;
    int lm = lane & 15, lq = lane >> 4;
    int row0 = blockIdx.x * GM;
    int n0   = wave * 32;

    // stage the block's 146 contiguous rowptr entries (rows' bins are adjacent)
    for (int i = tid; i < GM * NREL + 2; i += 256) {
        int g = row0 * NREL + i;
        rp_s[i] = rowptr[(g < NBINS) ? g : NBINS];
    }
    __syncthreads();

    // ---- gather: one walk per row, 16 lanes x 8 cols, r-tracked flushes ----
    int grow = tid >> 4;          // 0..15 dest row
    int cg   = tid & 15;          // 8-col group (16 B/lane; team covers the full 256 B row)
    int rbase = grow * NREL;
    int rs = rp_s[rbase];
    int re = rp_s[rbase + NREL];
    int r  = 0;
    int rnext = rp_s[rbase + 1];
    const short* hb = Hin + cg * 8;
    short* prow = &As[grow * KPITCH + cg * 8];

    float a[8];
#pragma unroll
    for (int k = 0; k < 8; k++) a[k] = 0.f;

#define FLUSH_SLICE  {                                                      \
        short8 o;                                                           \
        _Pragma("unroll")                                                   \
        for (int k = 0; k < 8; k++) o[k] = f2bf(a[k]);                      \
        *(short8*)(prow + r * HID) = o;                                     \
        _Pragma("unroll")                                                   \
        for (int k = 0; k < 8; k++) a[k] = 0.f;                             \
        r++;                                                                \
        rnext = rp_s[rbase + r + 1];                                        \
    }

    int j = rs;
    while (j < re) {
        int s_[8];
#pragma unroll
        for (int t = 0; t < 8; t++) s_[t] = bsrc[j + t];   // pad-safe (+8 zeros)
        short8 v[8];
#pragma unroll
        for (int t = 0; t < 8; t++)
            v[t] = *(const short8*)(hb + (size_t)s_[t] * HID);  // 8 loads in flight
#pragma unroll
        for (int t = 0; t < 8; t++) {
            int jt = j + t;
            if (jt < re) {
                while (jt >= rnext) FLUSH_SLICE;
#pragma unroll
                for (int k = 0; k < 8; k++) a[k] += bf2f(v[t][k]);
            }
        }
        j += 8;
    }
    while (r < NREL) FLUSH_SLICE;     // trailing flush + zero empty slices
#undef FLUSH_SLICE

    __syncthreads();   // panel complete

    // ---- MFMA sweep: A from LDS (M=16), B streamed from L2 ----
    f32x4 acc[2];
    acc[0] = (f32x4){0.f, 0.f, 0.f, 0.f};
    acc[1] = (f32x4){0.f, 0.f, 0.f, 0.f};

    const short* wb0 = Wt2l + (size_t)(n0 + lm) * KTOT + lq * 8;
    const short* wb1 = wb0 + (size_t)16 * KTOT;

#pragma unroll 4
    for (int kc = 0; kc < KTOT / 32; kc++) {      // 36 chunks
        short8 b0 = *(const short8*)(wb0 + kc * 32);
        short8 b1 = *(const short8*)(wb1 + kc * 32);
        short8 af = *(const short8*)&As[lm * KPITCH + kc * 32 + lq * 8];
        __builtin_amdgcn_s_setprio(1);
        acc[0] = __builtin_amdgcn_mfma_f32_16x16x32_bf16(af, b0, acc[0], 0, 0, 0);
        acc[1] = __builtin_amdgcn_mfma_f32_16x16x32_bf16(af, b1, acc[1], 0, 0, 0);
        __builtin_amdgcn_s_setprio(0);
    }
    __syncthreads();   // panel reads done; safe to reuse As as Et

    // ---- epilogue: counts-weighted bias (global, L2-hot), activation, store ----
    if (!last) {
        short (*Et)[FPITCH] = (short(*)[FPITCH])&As[0];
#pragma unroll
        for (int reg = 0; reg < 4; reg++) {
            int rl = lq * 4 + reg;
            float cr[NREL];
#pragma unroll
            for (int rr = 0; rr < NREL; rr++)
                cr[rr] = (float)(rp_s[rl * NREL + rr + 1] - rp_s[rl * NREL + rr]);
#pragma unroll
            for (int nt = 0; nt < 2; nt++) {
                int n = n0 + nt * 16 + lm;
                float b = 0.f;
#pragma unroll
                for (int rr = 0; rr < NREL; rr++) b += cr[rr] * Bias[rr * HID + n];
                float o = fmaxf(acc[nt][reg] + b, 0.f);
                Et[rl][n] = f2bf(o);
            }
        }
        __syncthreads();
        {
            int row = tid >> 4, cc = tid & 15;
            int d = row0 + row;
            *(short8*)(HoutBf + (size_t)d * HID + cc * 8) = *(const short8*)&Et[row][cc * 8];
        }
    } else {
#pragma unroll
        for (int reg = 0; reg < 4; reg++) {
            int rl = lq * 4 + reg;
            int d  = row0 + rl;
            float cr[NREL];
#pragma unroll
            for (int rr = 0; rr < NREL; rr++)
                cr[rr] = (float)(rp_s[rl * NREL + rr + 1] - rp_s[rl * NREL + rr]);
#pragma unroll
            for (int nt = 0; nt < 2; nt++) {
                int n = n0 + nt * 16 + lm;
                float b = 0.f;
#pragma unroll
                for (int rr = 0; rr < NREL; rr++) b += cr[rr] * Bias[rr * HID + n];
                HoutF[(size_t)d * HID + n] = acc[nt][reg] + b;
            }
        }
    }
}

// ---------------- driver ----------------

extern "C" void kernel_launch(void* const* d_in, const int* in_sizes, int n_in,
                              void* d_out, int out_size, void* d_ws, size_t ws_size,
                              hipStream_t stream) {
    const int*   edge_index = (const int*)d_in[0];   // [2, NEDGES]: row0=dest, row1=src
    const int*   etype      = (const int*)d_in[1];
    const float* emb        = (const float*)d_in[2];
    const float* W          = (const float*)d_in[3]; // [3,9,128,128]
    const float* Bias       = (const float*)d_in[4]; // [3,9,128]
    float*       out        = (float*)d_out;

    const int* dst  = edge_index;
    const int* srcA = edge_index + NEDGES;

    // ws layout (no S; H double-buffered)
    short* Ebf  = (short*)d_ws;                             // 50000*128 bf16
    short* HbfA = Ebf  + (size_t)NNODES * HID;              // 50000*128 bf16
    short* HbfB = HbfA + (size_t)NNODES * HID;              // 50000*128 bf16
    short* Wt2  = HbfB + (size_t)NNODES * HID;              // 3*128*1152 bf16
    int*   bsrc     = (int*)(Wt2 + (size_t)NLAYERS * HID * KTOT);  // NEDGES + 8 pad
    int*   bins     = bsrc + NEDGES + 8;
    int*   cursor   = bins + NBINS;
    int*   rowptr   = cursor + NBINS;                       // NBINS+1
    int*   blocksum = rowptr + NBINS + 1;
    int*   blockoff = blocksum + NBLK;

    hipMemsetAsync(bins, 0, NBINS * sizeof(int), stream);
    prep_kernel<<<HIST_BLKS + EMB_BLKS + W_BLKS, 256, 0, stream>>>(
        dst, etype, bins, emb, Ebf, W, Wt2);
    scan_pass1<<<NBLK, 256, 0, stream>>>(bins, blocksum);
    scan_pass2<<<1, 512, 0, stream>>>(blocksum, blockoff, rowptr);
    scan_pass3<<<NBLK, 256, 0, stream>>>(bins, blockoff, rowptr, cursor);
    place_kernel<<<(NEDGES + 255) / 256, 256, 0, stream>>>(dst, srcA, etype, cursor, bsrc);

    const int nblocks = NNODES / GM;   // 3125 (exact)
    const short* Hin = Ebf;
    for (int l = 0; l < NLAYERS; l++) {
        int last = (l + 1 == NLAYERS);
        short* Hout = (l == 0) ? HbfA : HbfB;       // alternate; never in-place
        if (l == 2) Hout = HbfA;                    // unused on last layer
        const short* Wtl = Wt2 + (size_t)l * HID * KTOT;
        const float* Bl  = Bias + (size_t)l * NREL * HID;
        fused_kernel<<<nblocks, 256, 0, stream>>>(
            Hin, Wtl, Bl, rowptr, bsrc, Hout, out, last);
        Hin = Hout;
    }
}